// Round 3
// baseline (1225.899 us; speedup 1.0000x reference)
//
#include <hip/hip_runtime.h>

// SelfAttentionBlock: x[8,2048,512]; Wq/Wk/Wv [512,512]; bq/bk/bv [512].
// out[8,2048,1024] = concat(x, causal_softmax(QK^T/sqrt(512)) @ V).
// Input/output dtype (fp32 vs bf16) detected at runtime on-device; all internal
// compute in bf16 MFMA with fp32 accumulation.

#define DEV __device__ __forceinline__

typedef unsigned short u16;
typedef unsigned int u32;
typedef __attribute__((ext_vector_type(8))) short short8;   // 8 bf16 = 4 VGPRs (MFMA A/B frag)
typedef __attribute__((ext_vector_type(4))) float float4v;  // MFMA C/D frag

DEV u16 f2bf(float f) {            // round-to-nearest-even fp32 -> bf16
    u32 u = __float_as_uint(f);
    return (u16)((u + 0x7FFFu + ((u >> 16) & 1u)) >> 16);
}
DEV float bf2f(u16 h) { return __uint_as_float(((u32)h) << 16); }

DEV float4v mfma16(short8 a, short8 b, float4v c) {
    return __builtin_amdgcn_mfma_f32_16x16x32_bf16(a, b, c, 0, 0, 0);
}

// ---------------- Kernel 0: detect input dtype ------------------------------
__global__ void detect_k(const u32* __restrict__ xw, int* __restrict__ flag) {
    __shared__ int sh[256];
    int tid = threadIdx.x;
    u32 w = xw[tid * 64];
    int e = (w >> 7) & 0xFF;
    sh[tid] = (e >= 0x60 && e <= 0x90) ? 1 : 0;
    __syncthreads();
    for (int s = 128; s > 0; s >>= 1) {
        if (tid < s) sh[tid] += sh[tid + s];
        __syncthreads();
    }
    if (tid == 0) flag[0] = (sh[0] > 128) ? 1 : 0;   // 1 = bf16 inputs/outputs
}

// ---------------- Kernel 1: canonicalize x to bf16 --------------------------
__global__ void convx_k(const void* __restrict__ x, const int* __restrict__ flag,
                        u16* __restrict__ xb) {
    int i0 = (blockIdx.x * 256 + threadIdx.x) * 8;
    if (flag[0]) {
        *(uint4*)&xb[i0] = *(const uint4*)((const u16*)x + i0);
    } else {
        const float* xf = (const float*)x;
        float4 f0 = *(const float4*)(xf + i0);
        float4 f1 = *(const float4*)(xf + i0 + 4);
        union { u16 us[8]; uint4 v; } pk;
        pk.us[0] = f2bf(f0.x); pk.us[1] = f2bf(f0.y);
        pk.us[2] = f2bf(f0.z); pk.us[3] = f2bf(f0.w);
        pk.us[4] = f2bf(f1.x); pk.us[5] = f2bf(f1.y);
        pk.us[6] = f2bf(f1.z); pk.us[7] = f2bf(f1.w);
        *(uint4*)&xb[i0] = pk.v;
    }
}

// ---------------- Kernel 2: transpose + canonicalize weights ----------------
__global__ void convw_k(const void* __restrict__ Wq, const void* __restrict__ Wk,
                        const void* __restrict__ Wv, const int* __restrict__ flag,
                        u16* __restrict__ Wt) {
    int z = blockIdx.y;
    const void* W = (z == 0) ? Wq : ((z == 1) ? Wk : Wv);
    int flat = blockIdx.x * 256 + threadIdx.x;   // = n*512 + k
    int n = flat >> 9, k = flat & 511;
    u16 v = flag[0] ? ((const u16*)W)[k * 512 + n]
                    : f2bf(((const float*)W)[k * 512 + n]);
    Wt[z * 262144 + flat] = v;
}

// ---------------- Kernel 3: canonicalize biases -----------------------------
__global__ void convb_k(const void* __restrict__ bq, const void* __restrict__ bk,
                        const void* __restrict__ bv, const int* __restrict__ flag,
                        u16* __restrict__ bb) {
    int i = blockIdx.x * 256 + threadIdx.x;      // 0..1535
    int z = i >> 9, n = i & 511;
    const void* s = (z == 0) ? bq : ((z == 1) ? bk : bv);
    bb[i] = flag[0] ? ((const u16*)s)[n] : f2bf(((const float*)s)[n]);
}

// ---------------- Kernel 4: copy x into out[..., 0:512] ---------------------
__global__ void xcopy_k(const u16* __restrict__ xb, const int* __restrict__ flag,
                        void* __restrict__ out) {
    int flat = (blockIdx.x * 256 + threadIdx.x) * 8;
    int row = flat >> 9, col = flat & 511;
    uint4 v = *(const uint4*)&xb[flat];
    if (flag[0]) {
        *(uint4*)((u16*)out + (size_t)row * 1024 + col) = v;
    } else {
        const u16* us = (const u16*)&v;
        float* o = (float*)out + (size_t)row * 1024 + col;
        float4 a, b;
        a.x = bf2f(us[0]); a.y = bf2f(us[1]); a.z = bf2f(us[2]); a.w = bf2f(us[3]);
        b.x = bf2f(us[4]); b.y = bf2f(us[5]); b.z = bf2f(us[6]); b.w = bf2f(us[7]);
        *(float4*)o = a; *(float4*)(o + 4) = b;
    }
}

// ---------------- Kernel 5: QKV projection GEMM -----------------------------
__global__ __launch_bounds__(256) void proj_k(
        const u16* __restrict__ x, const u16* __restrict__ Wt,
        const u16* __restrict__ bb,
        u16* __restrict__ Qo, u16* __restrict__ Ko, u16* __restrict__ Vt_out) {
    int z = blockIdx.z;
    const u16* Wz = Wt + z * 262144;                       // Wz[n][k]
    const u16* bias = bb + z * 512;
    int mBase = blockIdx.x * 128;
    int nBase = blockIdx.y * 128;

    __shared__ __attribute__((aligned(16))) u16 Xs[128 * 32];
    __shared__ __attribute__((aligned(16))) u16 Ws[128 * 32];

    int tid = threadIdx.x;
    int w = tid >> 6, lane = tid & 63, quad = lane >> 4, l16 = lane & 15;
    int wr = (w >> 1) * 64, wc = (w & 1) * 64;

    float4v acc[4][4] = {};                                // [mt][nt]

    for (int k0 = 0; k0 < 512; k0 += 32) {
        int flat0 = tid * 8;
        int row = flat0 >> 5, col = flat0 & 31;
        *(uint4*)&Xs[flat0]        = *(const uint4*)&x [(size_t)(mBase + row)      * 512 + k0 + col];
        *(uint4*)&Xs[flat0 + 2048] = *(const uint4*)&x [(size_t)(mBase + 64 + row) * 512 + k0 + col];
        *(uint4*)&Ws[flat0]        = *(const uint4*)&Wz[(size_t)(nBase + row)      * 512 + k0 + col];
        *(uint4*)&Ws[flat0 + 2048] = *(const uint4*)&Wz[(size_t)(nBase + 64 + row) * 512 + k0 + col];
        __syncthreads();

        short8 a[4], b[4];
        #pragma unroll
        for (int mt = 0; mt < 4; mt++)
            a[mt] = *(const short8*)&Xs[(wr + mt * 16 + l16) * 32 + quad * 8];
        #pragma unroll
        for (int nt = 0; nt < 4; nt++)
            b[nt] = *(const short8*)&Ws[(wc + nt * 16 + l16) * 32 + quad * 8];
        #pragma unroll
        for (int mt = 0; mt < 4; mt++)
            #pragma unroll
            for (int nt = 0; nt < 4; nt++)
                acc[mt][nt] = mfma16(a[mt], b[nt], acc[mt][nt]);
        __syncthreads();
    }

    #pragma unroll
    for (int nt = 0; nt < 4; nt++) {
        int n = nBase + wc + nt * 16 + l16;
        float bval = bf2f(bias[n]);
        #pragma unroll
        for (int mt = 0; mt < 4; mt++) {
            int m0 = mBase + wr + mt * 16 + quad * 4;
            float4v v = acc[mt][nt];
            if (z == 2) {
                int bbi = m0 >> 11, tt = m0 & 2047;        // Vt[b][d=n][t]
                u16 t0 = f2bf(v[0] + bval), t1 = f2bf(v[1] + bval);
                u16 t2 = f2bf(v[2] + bval), t3 = f2bf(v[3] + bval);
                uint2 pk = make_uint2((u32)t0 | ((u32)t1 << 16), (u32)t2 | ((u32)t3 << 16));
                *(uint2*)&Vt_out[((size_t)bbi * 512 + n) * 2048 + tt] = pk;
            } else {
                u16* dst = (z == 0) ? Qo : Ko;
                #pragma unroll
                for (int r = 0; r < 4; r++)
                    dst[(size_t)(m0 + r) * 512 + n] = f2bf(v[r] + bval);
            }
        }
    }
}

// ---------------- Kernel 6: flash attention v3 ------------------------------
// Br=64 q-rows/block, grid 32x8 = 256 blocks (1/CU). Each wave owns 16 q-rows
// end-to-end: S (Q in regs, K chunks in LDS), in-register online softmax
// (shfl over l16), per-wave LDS P-transpose (no block sync), PV with V chunks.
// K/V staged in double-buffered 16KB chunks (128-d granules), ONE barrier per
// chunk (8 per 64-key k-tile). LDS strides 136/72 pad away bank conflicts.
#define KSTR 136
#define VSTR 72
#define CHW  9216   // u16 per chunk buffer (max of 64*136=8704, 128*72=9216)

__global__ __launch_bounds__(256) void attn_k(
        const u16* __restrict__ Q, const u16* __restrict__ K,
        const u16* __restrict__ Vt, const int* __restrict__ flag,
        void* __restrict__ out) {
    int b = blockIdx.y;
    int qt = blockIdx.x;
    int q0 = qt * 64;
    int isbf = flag[0];

    __shared__ __attribute__((aligned(16))) u16 KVs[2][CHW];   // 36 KB
    __shared__ __attribute__((aligned(16))) u16 Ps[4][16 * 64]; // 8 KB

    int tid = threadIdx.x;
    int w = tid >> 6, lane = tid & 63, quad = lane >> 4, l16 = lane & 15;
    int row0 = w * 16;                         // wave's q-row block

    const u16* Qb = Q  + (size_t)b * 2048 * 512;
    const u16* Kb = K  + (size_t)b * 2048 * 512;
    const u16* Vb = Vt + (size_t)b * 512 * 2048;

    // Q fragments in registers: A[m=l16][k = ck*32 + quad*8], ck = 0..15
    short8 qf[16];
    {
        const u16* Qrow = &Qb[(size_t)(q0 + row0 + l16) * 512];
        #pragma unroll
        for (int ck = 0; ck < 16; ck++)
            qf[ck] = *(const short8*)&Qrow[ck * 32 + quad * 8];
    }

    float4v accO[32] = {};                     // rows: row0+quad*4+r, col d = j*16+l16
    float4v accS[4] = {};                      // cols: nt*16+l16 of current k-tile
    float mrow[4] = {-1e30f, -1e30f, -1e30f, -1e30f};
    float lrow[4] = {0.f, 0.f, 0.f, 0.f};

    const float scale = 0.044194173824159216f; // 1/sqrt(512)
    int nIter = qt + 1;
    int NC = nIter * 8;                        // chunks: per tile 4 K then 4 V

    uint4 ld[4];
    // prefetch chunk 0 (K, kt=0, c=0)
    #pragma unroll
    for (int i = 0; i < 4; i++) {
        int f = tid + 256 * i, row = f >> 4, col8 = f & 15;
        ld[i] = *(const uint4*)&Kb[(size_t)row * 512 + col8 * 8];
    }
    #pragma unroll
    for (int i = 0; i < 4; i++) {
        int f = tid + 256 * i, row = f >> 4, col8 = f & 15;
        *(uint4*)&KVs[0][row * KSTR + col8 * 8] = ld[i];
    }
    __syncthreads();

    for (int s = 0; s < NC; s++) {
        int p = s & 1;
        // ---- issue global loads for chunk s+1 ----
        int have = (s + 1 < NC);
        if (have) {
            int s2 = s + 1;
            int kt2 = s2 >> 3, ph2 = (s2 >> 2) & 1, c2 = s2 & 3, kB2 = kt2 * 64;
            if (ph2 == 0) {
                #pragma unroll
                for (int i = 0; i < 4; i++) {
                    int f = tid + 256 * i, row = f >> 4, col8 = f & 15;
                    ld[i] = *(const uint4*)&Kb[(size_t)(kB2 + row) * 512 + c2 * 128 + col8 * 8];
                }
            } else {
                #pragma unroll
                for (int i = 0; i < 4; i++) {
                    int f = tid + 256 * i, row = f >> 3, col8 = f & 7;
                    ld[i] = *(const uint4*)&Vb[(size_t)(c2 * 128 + row) * 2048 + kB2 + col8 * 8];
                }
            }
        }

        // ---- compute chunk s ----
        int kt = s >> 3, ph = (s >> 2) & 1, c = s & 3;
        const u16* buf = KVs[p];
        if (ph == 0) {
            // S += Q(c-chunk) . K(c-chunk)^T
            #pragma unroll
            for (int kk = 0; kk < 4; kk++) {
                #pragma unroll
                for (int nt = 0; nt < 4; nt++) {
                    short8 bf = *(const short8*)&buf[(nt * 16 + l16) * KSTR + kk * 32 + quad * 8];
                    accS[nt] = mfma16(qf[c * 4 + kk], bf, accS[nt]);
                }
            }
            if (c == 3) {
                // ---- in-register online softmax for this wave's 16 rows ----
                int diag = (kt == qt);
                float pv[4][4], alpha[4];
                #pragma unroll
                for (int r = 0; r < 4; r++) {
                    float mx = -1e30f;
                    #pragma unroll
                    for (int nt = 0; nt < 4; nt++) {
                        float sv = accS[nt][r] * scale;
                        if (diag && (nt * 16 + l16 > row0 + quad * 4 + r)) sv = -1e30f;
                        pv[nt][r] = sv;
                        mx = fmaxf(mx, sv);
                    }
                    mx = fmaxf(mx, __shfl_xor(mx, 1));
                    mx = fmaxf(mx, __shfl_xor(mx, 2));
                    mx = fmaxf(mx, __shfl_xor(mx, 4));
                    mx = fmaxf(mx, __shfl_xor(mx, 8));
                    float mnew = fmaxf(mrow[r], mx);
                    float a = __expf(mrow[r] - mnew);
                    float sum = 0.f;
                    #pragma unroll
                    for (int nt = 0; nt < 4; nt++) {
                        pv[nt][r] = __expf(pv[nt][r] - mnew);
                        sum += pv[nt][r];
                    }
                    sum += __shfl_xor(sum, 1);
                    sum += __shfl_xor(sum, 2);
                    sum += __shfl_xor(sum, 4);
                    sum += __shfl_xor(sum, 8);
                    lrow[r] = lrow[r] * a + sum;
                    mrow[r] = mnew;
                    alpha[r] = a;
                }
                bool need = (alpha[0] < 1.f) | (alpha[1] < 1.f) | (alpha[2] < 1.f) | (alpha[3] < 1.f);
                if (__any(need)) {
                    #pragma unroll
                    for (int j = 0; j < 32; j++)
                        #pragma unroll
                        for (int r = 0; r < 4; r++) accO[j][r] *= alpha[r];
                }
                // P (C-layout) -> per-wave LDS -> A-layout reads in PV phase
                #pragma unroll
                for (int nt = 0; nt < 4; nt++)
                    #pragma unroll
                    for (int r = 0; r < 4; r++)
                        Ps[w][(quad * 4 + r) * 64 + nt * 16 + l16] = f2bf(pv[nt][r]);
                #pragma unroll
                for (int nt = 0; nt < 4; nt++) accS[nt] = (float4v){0.f, 0.f, 0.f, 0.f};
            }
        } else {
            // O += P . V(c-chunk)   (V staged as Vt[d][key])
            short8 ap0 = *(const short8*)&Ps[w][l16 * 64 + quad * 8];
            short8 ap1 = *(const short8*)&Ps[w][l16 * 64 + 32 + quad * 8];
            #pragma unroll
            for (int nt = 0; nt < 8; nt++) {
                short8 b0 = *(const short8*)&buf[(nt * 16 + l16) * VSTR + quad * 8];
                short8 b1 = *(const short8*)&buf[(nt * 16 + l16) * VSTR + 32 + quad * 8];
                float4v t = mfma16(ap0, b0, accO[c * 8 + nt]);
                accO[c * 8 + nt] = mfma16(ap1, b1, t);
            }
        }

        // ---- commit staged chunk s+1 into the other buffer ----
        if (have) {
            int s2 = s + 1;
            int ph2 = (s2 >> 2) & 1;
            u16* dbuf = KVs[p ^ 1];
            if (ph2 == 0) {
                #pragma unroll
                for (int i = 0; i < 4; i++) {
                    int f = tid + 256 * i, row = f >> 4, col8 = f & 15;
                    *(uint4*)&dbuf[row * KSTR + col8 * 8] = ld[i];
                }
            } else {
                #pragma unroll
                for (int i = 0; i < 4; i++) {
                    int f = tid + 256 * i, row = f >> 3, col8 = f & 7;
                    *(uint4*)&dbuf[row * VSTR + col8 * 8] = ld[i];
                }
            }
        }
        __syncthreads();
    }

    // ---- epilogue: O /= l, write out[..., 512:1024] ----
    float invl[4];
    #pragma unroll
    for (int r = 0; r < 4; r++) invl[r] = 1.0f / lrow[r];
    u16*   o16 = (u16*)out;
    float* o32 = (float*)out;
    #pragma unroll
    for (int j = 0; j < 32; j++) {
        int dg = 512 + j * 16 + l16;
        #pragma unroll
        for (int r = 0; r < 4; r++) {
            int rowg = q0 + row0 + quad * 4 + r;
            size_t idx = ((size_t)b * 2048 + rowg) * 1024 + dg;
            float val = accO[j][r] * invl[r];
            if (isbf) o16[idx] = f2bf(val);
            else      o32[idx] = val;
        }
    }
}

// ---------------- launcher --------------------------------------------------
extern "C" void kernel_launch(void* const* d_in, const int* in_sizes, int n_in,
                              void* d_out, int out_size, void* d_ws, size_t ws_size,
                              hipStream_t stream) {
    const void* x  = d_in[0];
    const void* Wq = d_in[1];
    const void* bq = d_in[2];
    const void* Wk = d_in[3];
    const void* bk = d_in[4];
    const void* Wv = d_in[5];
    const void* bv = d_in[6];

    u16* base = (u16*)d_ws;
    int* flag = (int*)base;                         // 16 B
    u16* Wt   = base + 8;                           // 3*512*512 = 786432
    u16* bb   = Wt + 786432;                        // 1536 (pad to 1544)
    u16* xb   = bb + 1544;                          // 8,388,608
    u16* Qw   = xb + 8388608;
    u16* Kw   = Qw + 8388608;
    u16* Vtw  = Kw + 8388608;                       // total ~68.7 MB

    hipLaunchKernelGGL(detect_k, dim3(1), dim3(256), 0, stream, (const u32*)x, flag);
    hipLaunchKernelGGL(convx_k, dim3(4096), dim3(256), 0, stream, x, flag, xb);
    hipLaunchKernelGGL(convw_k, dim3(1024, 3), dim3(256), 0, stream, Wq, Wk, Wv, flag, Wt);
    hipLaunchKernelGGL(convb_k, dim3(6), dim3(256), 0, stream, bq, bk, bv, flag, bb);
    hipLaunchKernelGGL(xcopy_k, dim3(4096), dim3(256), 0, stream, xb, flag, d_out);
    hipLaunchKernelGGL(proj_k, dim3(128, 4, 3), dim3(256), 0, stream, xb, Wt, bb, Qw, Kw, Vtw);
    hipLaunchKernelGGL(attn_k, dim3(32, 8), dim3(256), 0, stream, Qw, Kw, Vtw, flag, d_out);
}

// Round 4
// 891.437 us; speedup vs baseline: 1.3752x; 1.3752x over previous
//
#include <hip/hip_runtime.h>

// SelfAttentionBlock: x[8,2048,512]; Wq/Wk/Wv [512,512]; bq/bk/bv [512].
// out[8,2048,1024] = concat(x, causal_softmax(QK^T/sqrt(512)) @ V).
// Runtime dtype detect (fp32 vs bf16); internal compute bf16 MFMA + fp32 acc.

#define DEV __device__ __forceinline__

typedef unsigned short u16;
typedef unsigned int u32;
typedef __attribute__((ext_vector_type(8))) short short8;   // 8 bf16 = 4 VGPRs
typedef __attribute__((ext_vector_type(4))) float float4v;  // MFMA C/D frag

DEV u16 f2bf(float f) {
    u32 u = __float_as_uint(f);
    return (u16)((u + 0x7FFFu + ((u >> 16) & 1u)) >> 16);
}
DEV float bf2f(u16 h) { return __uint_as_float(((u32)h) << 16); }

DEV float4v mfma16(short8 a, short8 b, float4v c) {
    return __builtin_amdgcn_mfma_f32_16x16x32_bf16(a, b, c, 0, 0, 0);
}

// async global->LDS, 16B per lane; LDS dest = wave-uniform base + lane*16
#define GLD16(gptr, lptr)                                                     \
    __builtin_amdgcn_global_load_lds(                                         \
        (const __attribute__((address_space(1))) void*)(gptr),                \
        (__attribute__((address_space(3))) void*)(lptr), 16, 0, 0)

// ---------------- Kernel 0: detect input dtype ------------------------------
__global__ void detect_k(const u32* __restrict__ xw, int* __restrict__ flag) {
    __shared__ int sh[256];
    int tid = threadIdx.x;
    u32 w = xw[tid * 64];
    int e = (w >> 7) & 0xFF;
    sh[tid] = (e >= 0x60 && e <= 0x90) ? 1 : 0;
    __syncthreads();
    for (int s = 128; s > 0; s >>= 1) {
        if (tid < s) sh[tid] += sh[tid + s];
        __syncthreads();
    }
    if (tid == 0) flag[0] = (sh[0] > 128) ? 1 : 0;   // 1 = bf16
}

// ---------------- Kernel 1: canonicalize x -> xb; also write out[...,0:512] -
__global__ void convx_k(const void* __restrict__ x, const int* __restrict__ flag,
                        u16* __restrict__ xb, void* __restrict__ out) {
    int i0 = (blockIdx.x * 256 + threadIdx.x) * 8;
    int row = i0 >> 9, col = i0 & 511;
    if (flag[0]) {
        uint4 v = *(const uint4*)((const u16*)x + i0);
        *(uint4*)&xb[i0] = v;
        *(uint4*)((u16*)out + (size_t)row * 1024 + col) = v;
    } else {
        const float* xf = (const float*)x;
        float4 f0 = *(const float4*)(xf + i0);
        float4 f1 = *(const float4*)(xf + i0 + 4);
        union { u16 us[8]; uint4 v; } pk;
        pk.us[0] = f2bf(f0.x); pk.us[1] = f2bf(f0.y);
        pk.us[2] = f2bf(f0.z); pk.us[3] = f2bf(f0.w);
        pk.us[4] = f2bf(f1.x); pk.us[5] = f2bf(f1.y);
        pk.us[6] = f2bf(f1.z); pk.us[7] = f2bf(f1.w);
        *(uint4*)&xb[i0] = pk.v;
        float* o = (float*)out + (size_t)row * 1024 + col;
        *(float4*)o = f0; *(float4*)(o + 4) = f1;      // exact copy of x
    }
}

// ---------------- Kernel 2: transpose + canonicalize weights ----------------
__global__ void convw_k(const void* __restrict__ Wq, const void* __restrict__ Wk,
                        const void* __restrict__ Wv, const int* __restrict__ flag,
                        u16* __restrict__ Wt) {
    int z = blockIdx.y;
    const void* W = (z == 0) ? Wq : ((z == 1) ? Wk : Wv);
    int flat = blockIdx.x * 256 + threadIdx.x;   // = n*512 + k
    int n = flat >> 9, k = flat & 511;
    u16 v = flag[0] ? ((const u16*)W)[k * 512 + n]
                    : f2bf(((const float*)W)[k * 512 + n]);
    Wt[z * 262144 + flat] = v;
}

// ---------------- Kernel 3: canonicalize biases -----------------------------
__global__ void convb_k(const void* __restrict__ bq, const void* __restrict__ bk,
                        const void* __restrict__ bv, const int* __restrict__ flag,
                        u16* __restrict__ bb) {
    int i = blockIdx.x * 256 + threadIdx.x;      // 0..1535
    int z = i >> 9, n = i & 511;
    const void* s = (z == 0) ? bq : ((z == 1) ? bk : bv);
    bb[i] = flag[0] ? ((const u16*)s)[n] : f2bf(((const float*)s)[n]);
}

// ---------------- Kernel 4: QKV projection GEMM (global_load_lds staging) ---
__global__ __launch_bounds__(256) void proj_k(
        const u16* __restrict__ x, const u16* __restrict__ Wt,
        const u16* __restrict__ bb,
        u16* __restrict__ Qo, u16* __restrict__ Ko, u16* __restrict__ Vt_out) {
    int z = blockIdx.z;
    const u16* Wz = Wt + z * 262144;                       // Wz[n][k]
    const u16* bias = bb + z * 512;
    int mBase = blockIdx.x * 128;
    int nBase = blockIdx.y * 128;

    __shared__ __attribute__((aligned(16))) u16 Xs[128 * 32];
    __shared__ __attribute__((aligned(16))) u16 Ws[128 * 32];

    int tid = threadIdx.x;
    int w = tid >> 6, lane = tid & 63, quad = lane >> 4, l16 = lane & 15;
    int wr = (w >> 1) * 64, wc = (w & 1) * 64;

    float4v acc[4][4] = {};

    for (int k0 = 0; k0 < 512; k0 += 32) {
        #pragma unroll
        for (int gg = 0; gg < 2; gg++) {                   // 1KB granules
            int g = w * 2 + gg;
            int row = g * 16 + (lane >> 2);
            int col8 = lane & 3;
            GLD16(&x [(size_t)(mBase + row) * 512 + k0 + col8 * 8], &Xs[g * 512]);
            GLD16(&Wz[(size_t)(nBase + row) * 512 + k0 + col8 * 8], &Ws[g * 512]);
        }
        __syncthreads();

        short8 a[4], b[4];
        #pragma unroll
        for (int mt = 0; mt < 4; mt++)
            a[mt] = *(const short8*)&Xs[(wr + mt * 16 + l16) * 32 + quad * 8];
        #pragma unroll
        for (int nt = 0; nt < 4; nt++)
            b[nt] = *(const short8*)&Ws[(wc + nt * 16 + l16) * 32 + quad * 8];
        #pragma unroll
        for (int mt = 0; mt < 4; mt++)
            #pragma unroll
            for (int nt = 0; nt < 4; nt++)
                acc[mt][nt] = mfma16(a[mt], b[nt], acc[mt][nt]);
        __syncthreads();
    }

    #pragma unroll
    for (int nt = 0; nt < 4; nt++) {
        int n = nBase + wc + nt * 16 + l16;
        float bval = bf2f(bias[n]);
        #pragma unroll
        for (int mt = 0; mt < 4; mt++) {
            int m0 = mBase + wr + mt * 16 + quad * 4;
            float4v v = acc[mt][nt];
            if (z == 2) {
                int bbi = m0 >> 11, tt = m0 & 2047;        // Vt[b][d=n][t]
                u16 t0 = f2bf(v[0] + bval), t1 = f2bf(v[1] + bval);
                u16 t2 = f2bf(v[2] + bval), t3 = f2bf(v[3] + bval);
                uint2 pk = make_uint2((u32)t0 | ((u32)t1 << 16), (u32)t2 | ((u32)t3 << 16));
                *(uint2*)&Vt_out[((size_t)bbi * 512 + n) * 2048 + tt] = pk;
            } else {
                u16* dst = (z == 0) ? Qo : Ko;
                #pragma unroll
                for (int r = 0; r < 4; r++)
                    dst[(size_t)(m0 + r) * 512 + n] = f2bf(v[r] + bval);
            }
        }
    }
}

// ---------------- Kernel 5: flash attention v4 ------------------------------
// grid 256: batch = blk&7 (XCD-local K/V in 4MB L2), qt = blk>>3. Bq=64, 4
// waves, wave owns 16 q-rows for S/softmax; PV d-split across waves (V read
// once). 32KB K/V chunks double-buffered via global_load_lds (async, issued
// one sub-phase ahead), XOR-swizzled LDS, 4 barriers/tile.
__global__ __launch_bounds__(256, 1) void attn_k(
        const u16* __restrict__ Q, const u16* __restrict__ K,
        const u16* __restrict__ Vt, const int* __restrict__ flag,
        void* __restrict__ out) {
    int blk = blockIdx.x;
    int b = blk & 7, qt = blk >> 3;
    int q0 = qt * 64;
    int isbf = flag[0];

    __shared__ __attribute__((aligned(16))) u16 KV[2][16384];   // 2 x 32 KB
    __shared__ __attribute__((aligned(16))) u16 Ps[4096];       // P 64x64 bf16
    __shared__ float al_s[64];
    __shared__ float il_s[64];

    int tid = threadIdx.x;
    int w = tid >> 6, lane = tid & 63, quad = lane >> 4, l16 = lane & 15;
    int sw = l16 & 7;                              // read-side XOR swizzle key

    const u16* Qb = Q  + (size_t)b * 2048 * 512;
    const u16* Kb = K  + (size_t)b * 2048 * 512;
    const u16* Vb = Vt + (size_t)b * 512 * 2048;

    int NS = (qt + 1) * 4;

    // ---- prefetch sub-phase 0: K tile0, d-half 0 -> buf 0 ----
    #pragma unroll
    for (int j = 0; j < 8; j++) {
        int row2 = 2 * (j * 4 + w);
        int row = row2 + (lane >> 5);
        int col8 = lane & 31;
        GLD16(&Kb[(size_t)row * 512 + ((col8 ^ (row & 7)) << 3)], &KV[0][row2 * 256]);
    }

    // ---- Q fragments in regs: rows w*16+l16, granule g = 32 d ----
    short8 qf[16];
    {
        const u16* Qrow = &Qb[(size_t)(q0 + w * 16 + l16) * 512];
        #pragma unroll
        for (int g = 0; g < 16; g++)
            qf[g] = *(const short8*)&Qrow[g * 32 + quad * 8];
    }

    float4v accO[2][4][4] = {};   // [c half][dt][mt]: d = c*256+w*64+dt*16+l16
    float4v accS[4] = {};         // keys nt*16+l16, rows w*16+quad*4+r
    short8 pf[4][2];              // P A-frags cached per tile
    float mrow[4] = {-1e30f, -1e30f, -1e30f, -1e30f};
    float lrow[4] = {0.f, 0.f, 0.f, 0.f};
    const float scale = 0.044194173824159216f;     // 1/sqrt(512)

    __syncthreads();

    for (int s = 0; s < NS; s++) {
        int p = s & 1;
        // ---- issue async loads for sub-phase s+1 into the other buffer ----
        int s2 = s + 1;
        if (s2 < NS) {
            int ph2 = s2 & 3, p2 = s2 & 1, kB2 = (s2 >> 2) << 6;
            if (ph2 < 2) {                                   // K, d-half ph2
                #pragma unroll
                for (int j = 0; j < 8; j++) {
                    int row2 = 2 * (j * 4 + w);
                    int row = row2 + (lane >> 5);
                    int col8 = lane & 31;
                    GLD16(&Kb[(size_t)(kB2 + row) * 512 + (ph2 & 1) * 256 +
                              ((col8 ^ (row & 7)) << 3)], &KV[p2][row2 * 256]);
                }
            } else {                                         // V, d-half ph2&1
                #pragma unroll
                for (int j = 0; j < 8; j++) {
                    int blk8 = 8 * (j * 4 + w);
                    int dl = blk8 + (lane >> 3);
                    int col8 = lane & 7;
                    GLD16(&Vb[(size_t)((ph2 & 1) * 256 + dl) * 2048 + kB2 +
                              ((col8 ^ (dl & 7)) << 3)], &KV[p2][blk8 * 64]);
                }
            }
        }

        // ---- compute on buffer p ----
        int ph = s & 3;
        const u16* buf = &KV[p][0];
        if (ph < 2) {
            // S += Q(half) . K(half)^T : 32 MFMAs
            #pragma unroll
            for (int kk = 0; kk < 8; kk++) {
                #pragma unroll
                for (int nt = 0; nt < 4; nt++) {
                    short8 bf = *(const short8*)&buf[(nt * 16 + l16) * 256 +
                                                     (((kk * 4 + quad) ^ sw) << 3)];
                    accS[nt] = mfma16(qf[ph * 8 + kk], bf, accS[nt]);
                }
            }
            if (ph == 1) {
                // ---- in-register online softmax (wave's 16 rows) ----
                int diag = ((s >> 2) == qt);
                float pv[4][4], alpha[4];
                #pragma unroll
                for (int r = 0; r < 4; r++) {
                    float mx = -1e30f;
                    #pragma unroll
                    for (int nt = 0; nt < 4; nt++) {
                        float sv = accS[nt][r] * scale;
                        if (diag && (nt * 16 + l16 > w * 16 + quad * 4 + r)) sv = -1e30f;
                        pv[nt][r] = sv;
                        mx = fmaxf(mx, sv);
                    }
                    mx = fmaxf(mx, __shfl_xor(mx, 1));
                    mx = fmaxf(mx, __shfl_xor(mx, 2));
                    mx = fmaxf(mx, __shfl_xor(mx, 4));
                    mx = fmaxf(mx, __shfl_xor(mx, 8));
                    float mnew = fmaxf(mrow[r], mx);
                    float a = __expf(mrow[r] - mnew);
                    float sum = 0.f;
                    #pragma unroll
                    for (int nt = 0; nt < 4; nt++) {
                        pv[nt][r] = __expf(pv[nt][r] - mnew);
                        sum += pv[nt][r];
                    }
                    sum += __shfl_xor(sum, 1);
                    sum += __shfl_xor(sum, 2);
                    sum += __shfl_xor(sum, 4);
                    sum += __shfl_xor(sum, 8);
                    lrow[r] = lrow[r] * a + sum;
                    mrow[r] = mnew;
                    alpha[r] = a;
                }
                #pragma unroll
                for (int nt = 0; nt < 4; nt++)
                    #pragma unroll
                    for (int r = 0; r < 4; r++)
                        Ps[(w * 16 + quad * 4 + r) * 64 + nt * 16 + l16] = f2bf(pv[nt][r]);
                #pragma unroll
                for (int r = 0; r < 4; r++) al_s[w * 16 + quad * 4 + r] = alpha[r];
                #pragma unroll
                for (int nt = 0; nt < 4; nt++) accS[nt] = (float4v){0.f, 0.f, 0.f, 0.f};
            }
        } else {
            int c = ph & 1;
            if (ph == 2) {
                // load P A-frags (all 64 rows) + rescale whole accO once/tile
                #pragma unroll
                for (int mt = 0; mt < 4; mt++)
                    #pragma unroll
                    for (int kk = 0; kk < 2; kk++)
                        pf[mt][kk] = *(const short8*)&Ps[(mt * 16 + l16) * 64 +
                                                         kk * 32 + quad * 8];
                float alf[4][4];
                #pragma unroll
                for (int mt = 0; mt < 4; mt++)
                    #pragma unroll
                    for (int r = 0; r < 4; r++)
                        alf[mt][r] = al_s[mt * 16 + quad * 4 + r];
                #pragma unroll
                for (int c2 = 0; c2 < 2; c2++)
                    #pragma unroll
                    for (int dt = 0; dt < 4; dt++)
                        #pragma unroll
                        for (int mt = 0; mt < 4; mt++)
                            #pragma unroll
                            for (int r = 0; r < 4; r++)
                                accO[c2][dt][mt][r] *= alf[mt][r];
            }
            // O(d-slice) += P . V : 32 MFMAs, V bytes read once per block
            #pragma unroll
            for (int kk = 0; kk < 2; kk++) {
                #pragma unroll
                for (int dt = 0; dt < 4; dt++) {
                    int rowv = w * 64 + dt * 16 + l16;
                    short8 bf = *(const short8*)&buf[rowv * 64 +
                                                     (((kk * 4 + quad) ^ sw) << 3)];
                    #pragma unroll
                    for (int mt = 0; mt < 4; mt++)
                        accO[c][dt][mt] = mfma16(pf[mt][kk], bf, accO[c][dt][mt]);
                }
            }
        }
        __syncthreads();
    }

    // ---- epilogue: share 1/l, write out[..., 512:1024] ----
    #pragma unroll
    for (int r = 0; r < 4; r++) il_s[w * 16 + quad * 4 + r] = 1.0f / lrow[r];
    __syncthreads();
    float invl[4][4];
    #pragma unroll
    for (int mt = 0; mt < 4; mt++)
        #pragma unroll
        for (int r = 0; r < 4; r++) invl[mt][r] = il_s[mt * 16 + quad * 4 + r];
    u16*   o16 = (u16*)out;
    float* o32 = (float*)out;
    #pragma unroll
    for (int c = 0; c < 2; c++)
        #pragma unroll
        for (int dt = 0; dt < 4; dt++) {
            int dg = 512 + c * 256 + w * 64 + dt * 16 + l16;
            #pragma unroll
            for (int mt = 0; mt < 4; mt++)
                #pragma unroll
                for (int r = 0; r < 4; r++) {
                    int rowg = q0 + mt * 16 + quad * 4 + r;
                    size_t idx = ((size_t)b * 2048 + rowg) * 1024 + dg;
                    float val = accO[c][dt][mt][r] * invl[mt][r];
                    if (isbf) o16[idx] = f2bf(val);
                    else      o32[idx] = val;
                }
        }
}

// ---------------- launcher --------------------------------------------------
extern "C" void kernel_launch(void* const* d_in, const int* in_sizes, int n_in,
                              void* d_out, int out_size, void* d_ws, size_t ws_size,
                              hipStream_t stream) {
    const void* x  = d_in[0];
    const void* Wq = d_in[1];
    const void* bq = d_in[2];
    const void* Wk = d_in[3];
    const void* bk = d_in[4];
    const void* Wv = d_in[5];
    const void* bv = d_in[6];

    u16* base = (u16*)d_ws;
    int* flag = (int*)base;                         // 16 B
    u16* Wt   = base + 8;                           // 3*512*512
    u16* bb   = Wt + 786432;                        // 1536 (pad 1544)
    u16* xb   = bb + 1544;                          // 8,388,608
    u16* Qw   = xb + 8388608;
    u16* Kw   = Qw + 8388608;
    u16* Vtw  = Kw + 8388608;                       // Vt[b][d][t]

    hipLaunchKernelGGL(detect_k, dim3(1), dim3(256), 0, stream, (const u32*)x, flag);
    hipLaunchKernelGGL(convx_k, dim3(4096), dim3(256), 0, stream, x, flag, xb, d_out);
    hipLaunchKernelGGL(convw_k, dim3(1024, 3), dim3(256), 0, stream, Wq, Wk, Wv, flag, Wt);
    hipLaunchKernelGGL(convb_k, dim3(6), dim3(256), 0, stream, bq, bk, bv, flag, bb);
    hipLaunchKernelGGL(proj_k, dim3(128, 4, 3), dim3(256), 0, stream, xb, Wt, bb, Qw, Kw, Vtw);
    hipLaunchKernelGGL(attn_k, dim3(256), dim3(256), 0, stream, Qw, Kw, Vtw, flag, d_out);
}

// Round 5
// 323.081 us; speedup vs baseline: 3.7944x; 2.7592x over previous
//
#include <hip/hip_runtime.h>

// SelfAttentionBlock: x[8,2048,512]; Wq/Wk/Wv [512,512]; bq/bk/bv [512].
// out[8,2048,1024] = concat(x, causal_softmax(QK^T/sqrt(512)) @ V).
// Runtime dtype detect (fp32 vs bf16); internal compute bf16 MFMA + fp32 acc.
// v5: attn phase loop fully statically unrolled -- NO runtime indexing of
// register arrays (v3/v4 spilled qf/accO to scratch: 1.3 GB HBM traffic).

#define DEV __device__ __forceinline__

typedef unsigned short u16;
typedef unsigned int u32;
typedef __attribute__((ext_vector_type(8))) short short8;   // 8 bf16 = 4 VGPRs
typedef __attribute__((ext_vector_type(4))) float float4v;  // MFMA C/D frag

DEV u16 f2bf(float f) {
    u32 u = __float_as_uint(f);
    return (u16)((u + 0x7FFFu + ((u >> 16) & 1u)) >> 16);
}
DEV float bf2f(u16 h) { return __uint_as_float(((u32)h) << 16); }

DEV float4v mfma16(short8 a, short8 b, float4v c) {
    return __builtin_amdgcn_mfma_f32_16x16x32_bf16(a, b, c, 0, 0, 0);
}

// async global->LDS, 16B per lane; LDS dest = wave-uniform base + lane*16
#define GLD16(gptr, lptr)                                                     \
    __builtin_amdgcn_global_load_lds(                                         \
        (const __attribute__((address_space(1))) void*)(gptr),                \
        (__attribute__((address_space(3))) void*)(lptr), 16, 0, 0)

// ---------------- Kernel 0: detect input dtype ------------------------------
__global__ void detect_k(const u32* __restrict__ xw, int* __restrict__ flag) {
    __shared__ int sh[256];
    int tid = threadIdx.x;
    u32 w = xw[tid * 64];
    int e = (w >> 7) & 0xFF;
    sh[tid] = (e >= 0x60 && e <= 0x90) ? 1 : 0;
    __syncthreads();
    for (int s = 128; s > 0; s >>= 1) {
        if (tid < s) sh[tid] += sh[tid + s];
        __syncthreads();
    }
    if (tid == 0) flag[0] = (sh[0] > 128) ? 1 : 0;   // 1 = bf16
}

// ---------------- Kernel 1: canonicalize x -> xb; also write out[...,0:512] -
__global__ void convx_k(const void* __restrict__ x, const int* __restrict__ flag,
                        u16* __restrict__ xb, void* __restrict__ out) {
    int i0 = (blockIdx.x * 256 + threadIdx.x) * 8;
    int row = i0 >> 9, col = i0 & 511;
    if (flag[0]) {
        uint4 v = *(const uint4*)((const u16*)x + i0);
        *(uint4*)&xb[i0] = v;
        *(uint4*)((u16*)out + (size_t)row * 1024 + col) = v;
    } else {
        const float* xf = (const float*)x;
        float4 f0 = *(const float4*)(xf + i0);
        float4 f1 = *(const float4*)(xf + i0 + 4);
        union { u16 us[8]; uint4 v; } pk;
        pk.us[0] = f2bf(f0.x); pk.us[1] = f2bf(f0.y);
        pk.us[2] = f2bf(f0.z); pk.us[3] = f2bf(f0.w);
        pk.us[4] = f2bf(f1.x); pk.us[5] = f2bf(f1.y);
        pk.us[6] = f2bf(f1.z); pk.us[7] = f2bf(f1.w);
        *(uint4*)&xb[i0] = pk.v;
        float* o = (float*)out + (size_t)row * 1024 + col;
        *(float4*)o = f0; *(float4*)(o + 4) = f1;
    }
}

// ---------------- Kernel 2: transpose + canonicalize weights ----------------
__global__ void convw_k(const void* __restrict__ Wq, const void* __restrict__ Wk,
                        const void* __restrict__ Wv, const int* __restrict__ flag,
                        u16* __restrict__ Wt) {
    int z = blockIdx.y;
    const void* W = (z == 0) ? Wq : ((z == 1) ? Wk : Wv);
    int flat = blockIdx.x * 256 + threadIdx.x;   // = n*512 + k
    int n = flat >> 9, k = flat & 511;
    u16 v = flag[0] ? ((const u16*)W)[k * 512 + n]
                    : f2bf(((const float*)W)[k * 512 + n]);
    Wt[z * 262144 + flat] = v;
}

// ---------------- Kernel 3: canonicalize biases -----------------------------
__global__ void convb_k(const void* __restrict__ bq, const void* __restrict__ bk,
                        const void* __restrict__ bv, const int* __restrict__ flag,
                        u16* __restrict__ bb) {
    int i = blockIdx.x * 256 + threadIdx.x;      // 0..1535
    int z = i >> 9, n = i & 511;
    const void* s = (z == 0) ? bq : ((z == 1) ? bk : bv);
    bb[i] = flag[0] ? ((const u16*)s)[n] : f2bf(((const float*)s)[n]);
}

// ---------------- Kernel 4: QKV projection GEMM -----------------------------
__global__ __launch_bounds__(256) void proj_k(
        const u16* __restrict__ x, const u16* __restrict__ Wt,
        const u16* __restrict__ bb,
        u16* __restrict__ Qo, u16* __restrict__ Ko, u16* __restrict__ Vt_out) {
    int z = blockIdx.z;
    const u16* Wz = Wt + z * 262144;                       // Wz[n][k]
    const u16* bias = bb + z * 512;
    int mBase = blockIdx.x * 128;
    int nBase = blockIdx.y * 128;

    __shared__ __attribute__((aligned(16))) u16 Xs[128 * 32];
    __shared__ __attribute__((aligned(16))) u16 Ws[128 * 32];

    int tid = threadIdx.x;
    int w = tid >> 6, lane = tid & 63, quad = lane >> 4, l16 = lane & 15;
    int wr = (w >> 1) * 64, wc = (w & 1) * 64;

    float4v acc[4][4] = {};

    for (int k0 = 0; k0 < 512; k0 += 32) {
        #pragma unroll
        for (int gg = 0; gg < 2; gg++) {                   // 1KB granules
            int g = w * 2 + gg;
            int row = g * 16 + (lane >> 2);
            int col8 = lane & 3;
            GLD16(&x [(size_t)(mBase + row) * 512 + k0 + col8 * 8], &Xs[g * 512]);
            GLD16(&Wz[(size_t)(nBase + row) * 512 + k0 + col8 * 8], &Ws[g * 512]);
        }
        __syncthreads();

        short8 a[4], b[4];
        #pragma unroll
        for (int mt = 0; mt < 4; mt++)
            a[mt] = *(const short8*)&Xs[(wr + mt * 16 + l16) * 32 + quad * 8];
        #pragma unroll
        for (int nt = 0; nt < 4; nt++)
            b[nt] = *(const short8*)&Ws[(wc + nt * 16 + l16) * 32 + quad * 8];
        #pragma unroll
        for (int mt = 0; mt < 4; mt++)
            #pragma unroll
            for (int nt = 0; nt < 4; nt++)
                acc[mt][nt] = mfma16(a[mt], b[nt], acc[mt][nt]);
        __syncthreads();
    }

    #pragma unroll
    for (int nt = 0; nt < 4; nt++) {
        int n = nBase + wc + nt * 16 + l16;
        float bval = bf2f(bias[n]);
        #pragma unroll
        for (int mt = 0; mt < 4; mt++) {
            int m0 = mBase + wr + mt * 16 + quad * 4;
            float4v v = acc[mt][nt];
            if (z == 2) {
                int bbi = m0 >> 11, tt = m0 & 2047;        // Vt[b][d=n][t]
                u16 t0 = f2bf(v[0] + bval), t1 = f2bf(v[1] + bval);
                u16 t2 = f2bf(v[2] + bval), t3 = f2bf(v[3] + bval);
                uint2 pk = make_uint2((u32)t0 | ((u32)t1 << 16), (u32)t2 | ((u32)t3 << 16));
                *(uint2*)&Vt_out[((size_t)bbi * 512 + n) * 2048 + tt] = pk;
            } else {
                u16* dst = (z == 0) ? Qo : Ko;
                #pragma unroll
                for (int r = 0; r < 4; r++)
                    dst[(size_t)(m0 + r) * 512 + n] = f2bf(v[r] + bval);
            }
        }
    }
}

// ---------------- Kernel 5: flash attention v5 ------------------------------
// grid 256: batch = blk&7 (XCD-local K/V), qt = blk>>3. Bq=64, 4 waves; wave
// owns 16 q-rows for S/softmax (Q in regs), PV d-split across waves. 32KB K/V
// chunks double-buffered (KV0/KV1) via async global_load_lds issued one phase
// ahead. Phases statically unrolled: all reg-array indices compile-time.

#define LOADK(dst, kB, half)                                                  \
    { _Pragma("unroll")                                                       \
      for (int j = 0; j < 8; j++) {                                           \
        int row2 = 2 * (j * 4 + w);                                           \
        int row = row2 + (lane >> 5);                                         \
        int col8 = lane & 31;                                                 \
        GLD16(&Kb[(size_t)((kB) + row) * 512 + (half) * 256 +                 \
                  ((col8 ^ (row & 7)) << 3)], &dst[row2 * 256]);              \
      } }

#define LOADV(dst, kB, half)                                                  \
    { _Pragma("unroll")                                                       \
      for (int j = 0; j < 8; j++) {                                           \
        int blk8 = 8 * (j * 4 + w);                                           \
        int dl = blk8 + (lane >> 3);                                          \
        int col8 = lane & 7;                                                  \
        GLD16(&Vb[(size_t)((half) * 256 + dl) * 2048 + (kB) +                 \
                  ((col8 ^ (dl & 7)) << 3)], &dst[blk8 * 64]);                \
      } }

#define SSTEP(buf, h)                                                         \
    { _Pragma("unroll")                                                       \
      for (int kk = 0; kk < 8; kk++) {                                        \
        _Pragma("unroll")                                                     \
        for (int nt = 0; nt < 4; nt++) {                                      \
          short8 bf = *(const short8*)&buf[(nt * 16 + l16) * 256 +            \
                                           (((kk * 4 + quad) ^ sw) << 3)];    \
          accS[nt] = mfma16(qf[(h) * 8 + kk], bf, accS[nt]);                  \
        } } }

#define PVSTEP(buf, accO)                                                     \
    { _Pragma("unroll")                                                       \
      for (int kk = 0; kk < 2; kk++) {                                        \
        _Pragma("unroll")                                                     \
        for (int dt = 0; dt < 4; dt++) {                                      \
          int rowv = w * 64 + dt * 16 + l16;                                  \
          short8 bf = *(const short8*)&buf[rowv * 64 +                        \
                                           (((kk * 4 + quad) ^ sw) << 3)];    \
          _Pragma("unroll")                                                   \
          for (int mt = 0; mt < 4; mt++)                                      \
            accO[dt][mt] = mfma16(pf[mt][kk], bf, accO[dt][mt]);              \
        } } }

__global__ __launch_bounds__(256, 1) void attn_k(
        const u16* __restrict__ Q, const u16* __restrict__ K,
        const u16* __restrict__ Vt, const int* __restrict__ flag,
        void* __restrict__ out) {
    int blk = blockIdx.x;
    int b = blk & 7, qt = blk >> 3;
    int q0 = qt * 64;
    int isbf = flag[0];

    __shared__ __attribute__((aligned(16))) u16 KV0[16384];   // 32 KB
    __shared__ __attribute__((aligned(16))) u16 KV1[16384];   // 32 KB
    __shared__ __attribute__((aligned(16))) u16 Ps[4096];     // P 64x64 bf16
    __shared__ float al_s[64];
    __shared__ float il_s[64];

    int tid = threadIdx.x;
    int w = tid >> 6, lane = tid & 63, quad = lane >> 4, l16 = lane & 15;
    int sw = l16 & 7;

    const u16* Qb = Q  + (size_t)b * 2048 * 512;
    const u16* Kb = K  + (size_t)b * 2048 * 512;
    const u16* Vb = Vt + (size_t)b * 512 * 2048;

    // prefetch tile0 K half0 -> KV0
    LOADK(KV0, 0, 0);

    // Q fragments in regs: rows w*16+l16, qf[g] = d-granule g (static idx only)
    short8 qf[16];
    {
        const u16* Qrow = &Qb[(size_t)(q0 + w * 16 + l16) * 512];
        #pragma unroll
        for (int g = 0; g < 16; g++)
            qf[g] = *(const short8*)&Qrow[g * 32 + quad * 8];
    }

    float4v accO0[4][4] = {};     // d = 0*256 + w*64 + dt*16 + l16
    float4v accO1[4][4] = {};     // d = 1*256 + w*64 + dt*16 + l16
    float4v accS[4] = {};         // keys nt*16+l16, rows w*16+quad*4+r
    short8 pf[4][2];
    float mrow[4] = {-1e30f, -1e30f, -1e30f, -1e30f};
    float lrow[4] = {0.f, 0.f, 0.f, 0.f};
    const float scale = 0.044194173824159216f;     // 1/sqrt(512)

    __syncthreads();

    for (int kt = 0; kt <= qt; kt++) {
        int kB = kt * 64;

        // ---- ph0: prefetch K half1 -> KV1; S += Q0.K0 from KV0 ----
        LOADK(KV1, kB, 1);
        SSTEP(KV0, 0);
        __syncthreads();

        // ---- ph1: prefetch V half0 -> KV0; S += Q1.K1 from KV1; softmax ----
        LOADV(KV0, kB, 0);
        SSTEP(KV1, 1);
        {
            int diag = (kt == qt);
            float pv[4][4], alpha[4];
            #pragma unroll
            for (int r = 0; r < 4; r++) {
                float mx = -1e30f;
                #pragma unroll
                for (int nt = 0; nt < 4; nt++) {
                    float sv = accS[nt][r] * scale;
                    if (diag && (nt * 16 + l16 > w * 16 + quad * 4 + r)) sv = -1e30f;
                    pv[nt][r] = sv;
                    mx = fmaxf(mx, sv);
                }
                mx = fmaxf(mx, __shfl_xor(mx, 1));
                mx = fmaxf(mx, __shfl_xor(mx, 2));
                mx = fmaxf(mx, __shfl_xor(mx, 4));
                mx = fmaxf(mx, __shfl_xor(mx, 8));
                float mnew = fmaxf(mrow[r], mx);
                float a = __expf(mrow[r] - mnew);
                float sum = 0.f;
                #pragma unroll
                for (int nt = 0; nt < 4; nt++) {
                    pv[nt][r] = __expf(pv[nt][r] - mnew);
                    sum += pv[nt][r];
                }
                sum += __shfl_xor(sum, 1);
                sum += __shfl_xor(sum, 2);
                sum += __shfl_xor(sum, 4);
                sum += __shfl_xor(sum, 8);
                lrow[r] = lrow[r] * a + sum;
                mrow[r] = mnew;
                alpha[r] = a;
            }
            #pragma unroll
            for (int nt = 0; nt < 4; nt++)
                #pragma unroll
                for (int r = 0; r < 4; r++)
                    Ps[(w * 16 + quad * 4 + r) * 64 + nt * 16 + l16] = f2bf(pv[nt][r]);
            #pragma unroll
            for (int r = 0; r < 4; r++) al_s[w * 16 + quad * 4 + r] = alpha[r];
            #pragma unroll
            for (int nt = 0; nt < 4; nt++) accS[nt] = (float4v){0.f, 0.f, 0.f, 0.f};
        }
        __syncthreads();

        // ---- ph2: prefetch V half1 -> KV1; P-frags + rescale; O0 += P.V0 ----
        LOADV(KV1, kB, 1);
        {
            #pragma unroll
            for (int mt = 0; mt < 4; mt++)
                #pragma unroll
                for (int kk = 0; kk < 2; kk++)
                    pf[mt][kk] = *(const short8*)&Ps[(mt * 16 + l16) * 64 +
                                                     kk * 32 + quad * 8];
            float alf[4][4];
            #pragma unroll
            for (int mt = 0; mt < 4; mt++)
                #pragma unroll
                for (int r = 0; r < 4; r++)
                    alf[mt][r] = al_s[mt * 16 + quad * 4 + r];
            #pragma unroll
            for (int dt = 0; dt < 4; dt++)
                #pragma unroll
                for (int mt = 0; mt < 4; mt++)
                    #pragma unroll
                    for (int r = 0; r < 4; r++) {
                        accO0[dt][mt][r] *= alf[mt][r];
                        accO1[dt][mt][r] *= alf[mt][r];
                    }
        }
        PVSTEP(KV0, accO0);
        __syncthreads();

        // ---- ph3: prefetch next K half0 -> KV0; O1 += P.V1 from KV1 ----
        if (kt < qt) LOADK(KV0, kB + 64, 0);
        PVSTEP(KV1, accO1);
        __syncthreads();
    }

    // ---- epilogue: share 1/l, write out[..., 512:1024] ----
    #pragma unroll
    for (int r = 0; r < 4; r++) il_s[w * 16 + quad * 4 + r] = 1.0f / lrow[r];
    __syncthreads();
    float invl[4][4];
    #pragma unroll
    for (int mt = 0; mt < 4; mt++)
        #pragma unroll
        for (int r = 0; r < 4; r++) invl[mt][r] = il_s[mt * 16 + quad * 4 + r];
    u16*   o16 = (u16*)out;
    float* o32 = (float*)out;
    #pragma unroll
    for (int dt = 0; dt < 4; dt++) {
        int dg0 = 512 + w * 64 + dt * 16 + l16;
        #pragma unroll
        for (int mt = 0; mt < 4; mt++)
            #pragma unroll
            for (int r = 0; r < 4; r++) {
                int rowg = q0 + mt * 16 + quad * 4 + r;
                size_t base = ((size_t)b * 2048 + rowg) * 1024;
                float v0 = accO0[dt][mt][r] * invl[mt][r];
                float v1 = accO1[dt][mt][r] * invl[mt][r];
                if (isbf) {
                    o16[base + dg0]       = f2bf(v0);
                    o16[base + dg0 + 256] = f2bf(v1);
                } else {
                    o32[base + dg0]       = v0;
                    o32[base + dg0 + 256] = v1;
                }
            }
    }
}

// ---------------- launcher --------------------------------------------------
extern "C" void kernel_launch(void* const* d_in, const int* in_sizes, int n_in,
                              void* d_out, int out_size, void* d_ws, size_t ws_size,
                              hipStream_t stream) {
    const void* x  = d_in[0];
    const void* Wq = d_in[1];
    const void* bq = d_in[2];
    const void* Wk = d_in[3];
    const void* bk = d_in[4];
    const void* Wv = d_in[5];
    const void* bv = d_in[6];

    u16* base = (u16*)d_ws;
    int* flag = (int*)base;                         // 16 B
    u16* Wt   = base + 8;                           // 3*512*512
    u16* bb   = Wt + 786432;                        // 1536 (pad 1544)
    u16* xb   = bb + 1544;                          // 8,388,608
    u16* Qw   = xb + 8388608;
    u16* Kw   = Qw + 8388608;
    u16* Vtw  = Kw + 8388608;                       // Vt[b][d][t]

    hipLaunchKernelGGL(detect_k, dim3(1), dim3(256), 0, stream, (const u32*)x, flag);
    hipLaunchKernelGGL(convx_k, dim3(4096), dim3(256), 0, stream, x, flag, xb, d_out);
    hipLaunchKernelGGL(convw_k, dim3(1024, 3), dim3(256), 0, stream, Wq, Wk, Wv, flag, Wt);
    hipLaunchKernelGGL(convb_k, dim3(6), dim3(256), 0, stream, bq, bk, bv, flag, bb);
    hipLaunchKernelGGL(proj_k, dim3(128, 4, 3), dim3(256), 0, stream, xb, Wt, bb, Qw, Kw, Vtw);
    hipLaunchKernelGGL(attn_k, dim3(256), dim3(256), 0, stream, Qw, Kw, Vtw, flag, d_out);
}